// Round 14
// baseline (193.275 us; speedup 1.0000x reference)
//
#include <hip/hip_runtime.h>
#include <hip/hip_bf16.h>

#define NB 4
#define CH 256
#define HH 64
#define WW 64
#define NPIX 4096      // HH*WW
#define OH 62
#define NPATCH 3844    // 62*62
#define KDIM 256       // == CH
#define EPSN 1e-12f
#define VROW 68        // V row stride (floats): 16B-aligned rows
#define SEG 16         // diagonal segment length (pairs per block)

typedef __attribute__((ext_vector_type(8))) short short8;
typedef __attribute__((ext_vector_type(4))) float f32x4;

__device__ __forceinline__ float bf16_to_f32(unsigned short u) {
    return __uint_as_float((unsigned)u << 16);
}
__device__ __forceinline__ unsigned short f32_to_bf16(float f) {
    __hip_bfloat16 h = __float2bfloat16(f);
    return *(unsigned short*)&h;
}

// ---- K1 (fused prep): read inputs ONCE; per-pixel ss + inv-norm; normalized bf16
// ---- transpose (C,pix)->(pix,C). Also zero-inits d_out + keys.
__global__ __launch_bounds__(256) void k_prep(const float* __restrict__ pred,
                                              const float* __restrict__ tgt,
                                              __hip_bfloat16* __restrict__ Xn,
                                              __hip_bfloat16* __restrict__ Tn,
                                              float* __restrict__ ssP, float* __restrict__ invP,
                                              float* __restrict__ ssT, float* __restrict__ invT,
                                              unsigned long long* __restrict__ keys,
                                              float* __restrict__ out) {
    const int bz = blockIdx.y;            // 0..7
    const int b = bz >> 1, which = bz & 1;
    const float* src = (which ? tgt : pred) + (size_t)b * CH * NPIX;
    unsigned short* dst = (unsigned short*)((which ? Tn : Xn) + (size_t)b * NPIX * CH);
    float* ss_g  = (which ? ssT  : ssP)  + b * NPIX;
    float* inv_g = (which ? invT : invP) + b * NPIX;
    const int pix0 = blockIdx.x * 64;
    const int t = threadIdx.x, lane = t & 63, wv = t >> 6;

    int gid = (bz * 64 + blockIdx.x) * 256 + t;
    if (gid < NB * NPATCH) keys[gid] = 0ull;
    if (gid == 0) out[0] = 0.f;

    __shared__ unsigned short stage[CH][65];   // bf16, +1 pad
    __shared__ float partial[4][64];
    __shared__ float inv_s[64];

    float ssacc = 0.f;
#pragma unroll 8
    for (int cc = 0; cc < 64; ++cc) {
        int c = wv * 64 + cc;
        float v = src[(size_t)c * NPIX + pix0 + lane];
        ssacc += v * v;
        stage[c][lane] = f32_to_bf16(v);
    }
    partial[wv][lane] = ssacc;
    __syncthreads();
    if (t < 64) {
        float ss = partial[0][t] + partial[1][t] + partial[2][t] + partial[3][t];
        float inv = 1.f / fmaxf(sqrtf(ss), EPSN);
        ss_g[pix0 + t] = ss;
        inv_g[pix0 + t] = inv;
        inv_s[t] = inv;
    }
    __syncthreads();
    for (int p = wv; p < 64; p += 4) {
        float iv = inv_s[p];
#pragma unroll
        for (int cb = 0; cb < 4; ++cb) {
            int c = cb * 64 + lane;
            float v = bf16_to_f32(stage[c][p]) * iv;
            dst[(size_t)(pix0 + p) * CH + c] = f32_to_bf16(v);
        }
    }
}

// ------- K2: D = Xn * Tn^T (4096x4096, K=256, bf16 MFMA, bf16 OUTPUT), z = batch.
// 512 thr / 8 waves, 32x64 per wave. BK=32 double-buffer (32 KB LDS -> 4 blocks/CU,
// staggered barrier phases) + XOR swizzle (R13-verified, conflicts = 0):
// LDS slot c of row r holds global k-chunk c^(r&3); fragment reads use
// slot = kq^(rsel&3) -> every bank group hit exactly 2x = free. D bit-identical.
__device__ __forceinline__ void gload_lds16(const void* g, void* l) {
    __builtin_amdgcn_global_load_lds(
        (const __attribute__((address_space(1))) void*)g,
        (__attribute__((address_space(3))) void*)l, 16, 0, 0);
}

__global__ __launch_bounds__(512) void k_gemm(const __hip_bfloat16* __restrict__ A,
                                              const __hip_bfloat16* __restrict__ Bm,
                                              unsigned short* __restrict__ Dout) {
    __shared__ short As[2][4096];   // [buf][row*32 + slot*8], 128 rows x BK=32
    __shared__ short Bs[2][4096];   // 32 KB total
    const int z = blockIdx.z;
    const int t = threadIdx.x;
    const int lane = t & 63, wv = t >> 6;          // 8 waves
    const int wm = wv >> 1, wn = wv & 1;           // 4x2 wave grid, 32x64 each
    const int row0 = blockIdx.y * 128, col0 = blockIdx.x * 128;
    const short* Ag = (const short*)A + (size_t)z * NPIX * CH;
    const short* Bg = (const short*)Bm + (size_t)z * NPIX * CH;
    unsigned short* D = Dout + (size_t)z * NPIX * NPIX;

    // staging: thread t covers row t>>2 (0..127), LDS slot t&3; fetches global
    // chunk (t&3)^(row&3). DMA dest = wave base + lane*16B == row*64B + slot*16B.
    const int srow = t >> 2;
    const int kce  = ((t & 3) ^ (srow & 3)) * 8;   // global element offset in BK=32

    f32x4 acc[2][4] = {};

#define STAGE_K(buf, k0)                                                               \
    do {                                                                               \
        gload_lds16(Ag + (size_t)(row0 + srow) * KDIM + (k0) + kce, &As[buf][wv * 512]); \
        gload_lds16(Bg + (size_t)(col0 + srow) * KDIM + (k0) + kce, &Bs[buf][wv * 512]); \
    } while (0)

    STAGE_K(0, 0);

    const int rsel = lane & 15, kq = lane >> 4;
    const int pk = (kq ^ (rsel & 3)) * 8;          // swizzled slot offset (shorts)
#pragma unroll
    for (int it = 0; it < 8; ++it) {
        __syncthreads();                            // buf[it&1] ready
        const int buf = it & 1;
        if (it < 7) STAGE_K(buf ^ 1, (it + 1) * 32);
        short8 a[2], bfr[4];
#pragma unroll
        for (int mi = 0; mi < 2; ++mi)
            a[mi] = *(const short8*)&As[buf][(wm * 32 + mi * 16 + rsel) * 32 + pk];
#pragma unroll
        for (int ni = 0; ni < 4; ++ni)
            bfr[ni] = *(const short8*)&Bs[buf][(wn * 64 + ni * 16 + rsel) * 32 + pk];
#pragma unroll
        for (int mi = 0; mi < 2; ++mi)
#pragma unroll
            for (int ni = 0; ni < 4; ++ni)
                acc[mi][ni] = __builtin_amdgcn_mfma_f32_16x16x32_bf16(a[mi], bfr[ni], acc[mi][ni], 0, 0, 0);
    }
#undef STAGE_K
    // C/D layout: col = lane&15, row = (lane>>4)*4 + reg (scalar stores; L2 coalesces)
    const int rbase = (lane >> 4) * 4, cbase = lane & 15;
#pragma unroll
    for (int mi = 0; mi < 2; ++mi) {
#pragma unroll
        for (int ni = 0; ni < 4; ++ni) {
            int r0 = row0 + wm * 32 + mi * 16 + rbase;
            int c  = col0 + wn * 64 + ni * 16 + cbase;
#pragma unroll
            for (int r = 0; r < 4; ++r)
                D[(size_t)(r0 + r) * NPIX + c] = f32_to_bf16(acc[mi][ni][r]);
        }
    }
}

__device__ __forceinline__ void load_tile16(const unsigned short* __restrict__ D,
                                            int row, int col, float* f) {
    const unsigned short* rp = D + (size_t)row * NPIX + col;
    uint4 u0 = *(const uint4*)rp;
    uint4 u1 = *(const uint4*)(rp + 8);
    const unsigned* w0 = (const unsigned*)&u0;
    const unsigned* w1 = (const unsigned*)&u1;
#pragma unroll
    for (int w = 0; w < 4; ++w) {
        f[2 * w]         = bf16_to_f32((unsigned short)w0[w]);
        f[2 * w + 1]     = bf16_to_f32((unsigned short)(w0[w] >> 16));
        f[8 + 2 * w]     = bf16_to_f32((unsigned short)w1[w]);
        f[8 + 2 * w + 1] = bf16_to_f32((unsigned short)(w1[w] >> 16));
    }
}

// ---- K3 (k_score): rolling diagonal segments + REGISTER PREFETCH. Tiles 0..2
// preloaded; during step k the load for tile k+3 is issued into ring slot P and
// only consumed after the full score phase -> the ~700-cyc global latency that
// was exposed once per step is now hidden. V-sum order unchanged (bit-identical).
__global__ __launch_bounds__(256) void k_score(const unsigned short* __restrict__ Dbase,
                                               unsigned long long* __restrict__ keys) {
    const int z = blockIdx.y;
    const unsigned short* D = Dbase + (size_t)z * NPIX * NPIX;
    const int t = threadIdx.x;

    const int bx = blockIdx.x;
    int d, s0;
    if (bx < 108)      { int q = bx >> 2;  d = q - 13;  s0 = (bx & 3) * SEG; }
    else if (bx < 204) { int r = bx - 108; int q = r / 3; int s = r - q * 3;
                         d = (q < 16) ? (14 + q) : -(q - 2);  s0 = s * SEG; }
    else if (bx < 268) { int r = bx - 204; int q = r >> 1;
                         d = (q < 16) ? (30 + q) : -(q + 14);  s0 = (r & 1) * SEG; }
    else               { int r = bx - 268;
                         d = (r < 16) ? (46 + r) : -(r + 30);  s0 = 0; }
    const int adg = d < 0 ? -d : d;
    const int len = 62 - adg;
    const int steps = min(SEG, len - s0);
    const int qr0 = (d > 0 ? d : 0) + s0;
    const int pr0 = qr0 - d;

    __shared__ __align__(16) float V[64 * VROW];   // 17408 B

    const int a = t >> 2, b0 = (t & 3) * 16;
    const int g = t >> 6, qc = t & 63;
    const int qcr = qc < OH ? qc : (OH - 1);
    const int pc0 = g * 16;
    const int kmax = (g == 3) ? 14 : 16;

    float A[16], B[16], C[16], P[16];
    load_tile16(D, (qr0 + 0) * 64 + a, (pr0 + 0) * 64 + b0, A);
    load_tile16(D, (qr0 + 1) * 64 + a, (pr0 + 1) * 64 + b0, B);
    load_tile16(D, (qr0 + 2) * 64 + a, (pr0 + 2) * 64 + b0, C);

    for (int k = 0; k < steps; ++k) {
        if (k + 1 < steps)                          // prefetch tile k+3 (used next step)
            load_tile16(D, (qr0 + k + 3) * 64 + a, (pr0 + k + 3) * 64 + b0, P);
        float v[16];
#pragma unroll
        for (int e = 0; e < 16; ++e) v[e] = A[e] + B[e] + C[e];
        if (k) __syncthreads();                    // step k-1 score reads done
#pragma unroll
        for (int e = 0; e < 16; e += 4)
            *(f32x4*)&V[a * VROW + b0 + e] = *(const f32x4*)&v[e];
        __syncthreads();

        float r0[16], r1[20], r2[20];
#pragma unroll
        for (int e = 0; e < 16; e += 4)
            *(f32x4*)&r0[e] = *(const f32x4*)&V[qcr * VROW + pc0 + e];
#pragma unroll
        for (int e = 0; e < 20; e += 4)
            *(f32x4*)&r1[e] = *(const f32x4*)&V[(qcr + 1) * VROW + pc0 + e];
#pragma unroll
        for (int e = 0; e < 20; e += 4)
            *(f32x4*)&r2[e] = *(const f32x4*)&V[(qcr + 2) * VROW + pc0 + e];
        float best = -1e30f; int bpc = 0;
#pragma unroll
        for (int kk = 0; kk < 16; ++kk) {
            float s = r0[kk] + r1[kk + 1] + r2[kk + 2];
            if (kk < kmax && s > best) { best = s; bpc = pc0 + kk; }
        }
        if (qc < OH) {
            unsigned u = __float_as_uint(best);
            u = (best >= 0.f) ? (u | 0x80000000u) : ~u;
            unsigned long long key = ((unsigned long long)u << 12)
                                   | (unsigned)((63 - (pr0 + k)) << 6)
                                   | (unsigned)(63 - bpc);
            atomicMax(&keys[(size_t)z * NPATCH + (qr0 + k) * OH + qc], key);
        }
        if (k + 1 < steps) {
#pragma unroll
            for (int e = 0; e < 16; ++e) { A[e] = B[e]; B[e] = C[e]; C[e] = P[e]; }
        }
    }
}

// -------- K4 (k_loss): decode keys -> match; loss via norm expansion --------
__global__ void k_loss(const unsigned short* __restrict__ Dbase,
                       const unsigned long long* __restrict__ keys,
                       const float* __restrict__ ssPb, const float* __restrict__ invPb,
                       const float* __restrict__ ssTb, const float* __restrict__ invTb,
                       float* __restrict__ out) {
    const int z = blockIdx.y;
    const unsigned short* D = Dbase + (size_t)z * NPIX * NPIX;
    const float* ssP  = ssPb  + z * NPIX;
    const float* invP = invPb + z * NPIX;
    const float* ssT  = ssTb  + z * NPIX;
    const float* invT = invTb + z * NPIX;
    int q = blockIdx.x * 256 + threadIdx.x;
    float acc = 0.f;
    if (q < NPATCH) {
        int qr = q / OH, qc = q - qr * OH;
        int qpix = qr * WW + qc;
        unsigned long long key = keys[(size_t)z * NPATCH + q];
        int mpr = 63 - (int)((key >> 6) & 63);
        int mpc = 63 - (int)(key & 63);
        int mpix = mpr * WW + mpc;
#pragma unroll
        for (int i = 0; i < 3; ++i)
#pragma unroll
            for (int j = 0; j < 3; ++j) {
                int off = i * WW + j;
                int y = qpix + off, x = mpix + off;
                float Dv = bf16_to_f32(D[(size_t)y * NPIX + x]);
                float nP = ssP[y] * invP[y];       // = ||p_y||
                float nT = ssT[x] * invT[x];
                acc += ssP[y] + ssT[x] - 2.f * Dv * nP * nT;
            }
    }
#pragma unroll
    for (int s = 32; s > 0; s >>= 1) acc += __shfl_down(acc, s, 64);
    if ((threadIdx.x & 63) == 0)
        atomicAdd(out, acc * (1.f / 35426304.f));  // / (4*3844*2304)
}

// ---------------------------------- launch ----------------------------------
extern "C" void kernel_launch(void* const* d_in, const int* in_sizes, int n_in,
                              void* d_out, int out_size, void* d_ws, size_t ws_size,
                              hipStream_t stream) {
    const float* pred = (const float*)d_in[0];
    const float* tgt  = (const float*)d_in[1];
    char* ws = (char*)d_ws;
    // ws layout (bytes), ws_size = 256 MiB:
    // D(bf16, 4 batches) 128MB | Xn 8MB | Tn 8MB | norms 4x64KB | keys 123KB
    unsigned short*     Dws  = (unsigned short*)(ws);
    __hip_bfloat16*     Xn   = (__hip_bfloat16*)(ws + 134217728);
    __hip_bfloat16*     Tn   = (__hip_bfloat16*)(ws + 142606336);
    float*              ssP  = (float*)(ws + 150994944);
    float*              invP = (float*)(ws + 151060480);
    float*              ssT  = (float*)(ws + 151126016);
    float*              invT = (float*)(ws + 151191552);
    unsigned long long* keys = (unsigned long long*)(ws + 151257088);

    k_prep<<<dim3(64, 8), 256, 0, stream>>>(pred, tgt, Xn, Tn, ssP, invP, ssT, invT,
                                            keys, (float*)d_out);
    k_gemm<<<dim3(32, 32, 4), 512, 0, stream>>>(Xn, Tn, Dws);
    k_score<<<dim3(300, 4), 256, 0, stream>>>(Dws, keys);
    k_loss<<<dim3(16, 4), 256, 0, stream>>>(Dws, keys, ssP, invP, ssT, invT,
                                            (float*)d_out);
}

// Round 15
// 182.212 us; speedup vs baseline: 1.0607x; 1.0607x over previous
//
#include <hip/hip_runtime.h>
#include <hip/hip_bf16.h>

#define NB 4
#define CH 256
#define HH 64
#define WW 64
#define NPIX 4096      // HH*WW
#define OH 62
#define NPATCH 3844    // 62*62
#define KDIM 256       // == CH
#define EPSN 1e-12f
#define VROW 68        // V row stride (floats): 16B-aligned rows
#define SEG 8          // diagonal segment length (pairs per block) — small = more TLP

typedef __attribute__((ext_vector_type(8))) short short8;
typedef __attribute__((ext_vector_type(4))) float f32x4;

__device__ __forceinline__ float bf16_to_f32(unsigned short u) {
    return __uint_as_float((unsigned)u << 16);
}
__device__ __forceinline__ unsigned short f32_to_bf16(float f) {
    __hip_bfloat16 h = __float2bfloat16(f);
    return *(unsigned short*)&h;
}

// ---- K1 (fused prep): read inputs ONCE; per-pixel ss + inv-norm; normalized bf16
// ---- transpose (C,pix)->(pix,C). Also zero-inits d_out + keys.
__global__ __launch_bounds__(256) void k_prep(const float* __restrict__ pred,
                                              const float* __restrict__ tgt,
                                              __hip_bfloat16* __restrict__ Xn,
                                              __hip_bfloat16* __restrict__ Tn,
                                              float* __restrict__ ssP, float* __restrict__ invP,
                                              float* __restrict__ ssT, float* __restrict__ invT,
                                              unsigned long long* __restrict__ keys,
                                              float* __restrict__ out) {
    const int bz = blockIdx.y;            // 0..7
    const int b = bz >> 1, which = bz & 1;
    const float* src = (which ? tgt : pred) + (size_t)b * CH * NPIX;
    unsigned short* dst = (unsigned short*)((which ? Tn : Xn) + (size_t)b * NPIX * CH);
    float* ss_g  = (which ? ssT  : ssP)  + b * NPIX;
    float* inv_g = (which ? invT : invP) + b * NPIX;
    const int pix0 = blockIdx.x * 64;
    const int t = threadIdx.x, lane = t & 63, wv = t >> 6;

    int gid = (bz * 64 + blockIdx.x) * 256 + t;
    if (gid < NB * NPATCH) keys[gid] = 0ull;
    if (gid == 0) out[0] = 0.f;

    __shared__ unsigned short stage[CH][65];   // bf16, +1 pad
    __shared__ float partial[4][64];
    __shared__ float inv_s[64];

    float ssacc = 0.f;
#pragma unroll 8
    for (int cc = 0; cc < 64; ++cc) {
        int c = wv * 64 + cc;
        float v = src[(size_t)c * NPIX + pix0 + lane];
        ssacc += v * v;
        stage[c][lane] = f32_to_bf16(v);
    }
    partial[wv][lane] = ssacc;
    __syncthreads();
    if (t < 64) {
        float ss = partial[0][t] + partial[1][t] + partial[2][t] + partial[3][t];
        float inv = 1.f / fmaxf(sqrtf(ss), EPSN);
        ss_g[pix0 + t] = ss;
        inv_g[pix0 + t] = inv;
        inv_s[t] = inv;
    }
    __syncthreads();
    for (int p = wv; p < 64; p += 4) {
        float iv = inv_s[p];
#pragma unroll
        for (int cb = 0; cb < 4; ++cb) {
            int c = cb * 64 + lane;
            float v = bf16_to_f32(stage[c][p]) * iv;
            dst[(size_t)(pix0 + p) * CH + c] = f32_to_bf16(v);
        }
    }
}

// ------- K2: D = Xn * Tn^T (4096x4096, K=256, bf16 MFMA, bf16 OUTPUT), z = batch.
// 512 thr / 8 waves, 32x64 per wave. BK=32 double-buffer (32 KB LDS -> 4 blocks/CU)
// + XOR swizzle (R13-verified, conflicts = 0). D bit-identical.
__device__ __forceinline__ void gload_lds16(const void* g, void* l) {
    __builtin_amdgcn_global_load_lds(
        (const __attribute__((address_space(1))) void*)g,
        (__attribute__((address_space(3))) void*)l, 16, 0, 0);
}

__global__ __launch_bounds__(512) void k_gemm(const __hip_bfloat16* __restrict__ A,
                                              const __hip_bfloat16* __restrict__ Bm,
                                              unsigned short* __restrict__ Dout) {
    __shared__ short As[2][4096];   // [buf][row*32 + slot*8], 128 rows x BK=32
    __shared__ short Bs[2][4096];   // 32 KB total
    const int z = blockIdx.z;
    const int t = threadIdx.x;
    const int lane = t & 63, wv = t >> 6;          // 8 waves
    const int wm = wv >> 1, wn = wv & 1;           // 4x2 wave grid, 32x64 each
    const int row0 = blockIdx.y * 128, col0 = blockIdx.x * 128;
    const short* Ag = (const short*)A + (size_t)z * NPIX * CH;
    const short* Bg = (const short*)Bm + (size_t)z * NPIX * CH;
    unsigned short* D = Dout + (size_t)z * NPIX * NPIX;

    const int srow = t >> 2;
    const int kce  = ((t & 3) ^ (srow & 3)) * 8;   // global element offset in BK=32

    f32x4 acc[2][4] = {};

#define STAGE_K(buf, k0)                                                               \
    do {                                                                               \
        gload_lds16(Ag + (size_t)(row0 + srow) * KDIM + (k0) + kce, &As[buf][wv * 512]); \
        gload_lds16(Bg + (size_t)(col0 + srow) * KDIM + (k0) + kce, &Bs[buf][wv * 512]); \
    } while (0)

    STAGE_K(0, 0);

    const int rsel = lane & 15, kq = lane >> 4;
    const int pk = (kq ^ (rsel & 3)) * 8;          // swizzled slot offset (shorts)
#pragma unroll
    for (int it = 0; it < 8; ++it) {
        __syncthreads();                            // buf[it&1] ready
        const int buf = it & 1;
        if (it < 7) STAGE_K(buf ^ 1, (it + 1) * 32);
        short8 a[2], bfr[4];
#pragma unroll
        for (int mi = 0; mi < 2; ++mi)
            a[mi] = *(const short8*)&As[buf][(wm * 32 + mi * 16 + rsel) * 32 + pk];
#pragma unroll
        for (int ni = 0; ni < 4; ++ni)
            bfr[ni] = *(const short8*)&Bs[buf][(wn * 64 + ni * 16 + rsel) * 32 + pk];
#pragma unroll
        for (int mi = 0; mi < 2; ++mi)
#pragma unroll
            for (int ni = 0; ni < 4; ++ni)
                acc[mi][ni] = __builtin_amdgcn_mfma_f32_16x16x32_bf16(a[mi], bfr[ni], acc[mi][ni], 0, 0, 0);
    }
#undef STAGE_K
    const int rbase = (lane >> 4) * 4, cbase = lane & 15;
#pragma unroll
    for (int mi = 0; mi < 2; ++mi) {
#pragma unroll
        for (int ni = 0; ni < 4; ++ni) {
            int r0 = row0 + wm * 32 + mi * 16 + rbase;
            int c  = col0 + wn * 64 + ni * 16 + cbase;
#pragma unroll
            for (int r = 0; r < 4; ++r)
                D[(size_t)(r0 + r) * NPIX + c] = f32_to_bf16(acc[mi][ni][r]);
        }
    }
}

__device__ __forceinline__ void load_tile16(const unsigned short* __restrict__ D,
                                            int row, int col, float* f) {
    const unsigned short* rp = D + (size_t)row * NPIX + col;
    uint4 u0 = *(const uint4*)rp;
    uint4 u1 = *(const uint4*)(rp + 8);
    const unsigned* w0 = (const unsigned*)&u0;
    const unsigned* w1 = (const unsigned*)&u1;
#pragma unroll
    for (int w = 0; w < 4; ++w) {
        f[2 * w]         = bf16_to_f32((unsigned short)w0[w]);
        f[2 * w + 1]     = bf16_to_f32((unsigned short)(w0[w] >> 16));
        f[8 + 2 * w]     = bf16_to_f32((unsigned short)w1[w]);
        f[8 + 2 * w + 1] = bf16_to_f32((unsigned short)(w1[w] >> 16));
    }
}

// ---- K3 (k_score): rolling diagonal segments, SEG=8, TLP-first. R14 post-mortem:
// register prefetch cost VGPR/occupancy and lost; instead, ~3900 light blocks
// (9 resident/CU, LDS-capped) hide each step's LLC latency with other blocks'
// work. Grid (123 diag, 8 chunk, 4 z), early-exit on short diagonals (~3% waste).
// V-sum order unchanged -> keys bit-identical.
__global__ __launch_bounds__(256) void k_score(const unsigned short* __restrict__ Dbase,
                                               unsigned long long* __restrict__ keys) {
    const int z = blockIdx.z;
    const unsigned short* D = Dbase + (size_t)z * NPIX * NPIX;
    const int t = threadIdx.x;

    const int d = (int)blockIdx.x - 61;            // diagonal qr-pr in [-61, 61]
    const int adg = d < 0 ? -d : d;
    const int len = 62 - adg;
    const int s0 = blockIdx.y * SEG;
    if (s0 >= len) return;
    const int steps = min(SEG, len - s0);
    const int qr0 = (d > 0 ? d : 0) + s0;
    const int pr0 = qr0 - d;

    __shared__ __align__(16) float V[64 * VROW];   // 17408 B -> 9 blocks/CU

    const int a = t >> 2, b0 = (t & 3) * 16;
    const int g = t >> 6, qc = t & 63;
    const int qcr = qc < OH ? qc : (OH - 1);
    const int pc0 = g * 16;
    const int kmax = (g == 3) ? 14 : 16;

    float A[16], B[16], C[16];
    load_tile16(D, (qr0 + 0) * 64 + a, (pr0 + 0) * 64 + b0, A);
    load_tile16(D, (qr0 + 1) * 64 + a, (pr0 + 1) * 64 + b0, B);

    for (int k = 0; k < steps; ++k) {
        load_tile16(D, (qr0 + k + 2) * 64 + a, (pr0 + k + 2) * 64 + b0, C);
        float v[16];
#pragma unroll
        for (int e = 0; e < 16; ++e) v[e] = A[e] + B[e] + C[e];
        if (k) __syncthreads();                    // step k-1 score reads done
#pragma unroll
        for (int e = 0; e < 16; e += 4)
            *(f32x4*)&V[a * VROW + b0 + e] = *(const f32x4*)&v[e];
        __syncthreads();

        float r0[16], r1[20], r2[20];
#pragma unroll
        for (int e = 0; e < 16; e += 4)
            *(f32x4*)&r0[e] = *(const f32x4*)&V[qcr * VROW + pc0 + e];
#pragma unroll
        for (int e = 0; e < 20; e += 4)
            *(f32x4*)&r1[e] = *(const f32x4*)&V[(qcr + 1) * VROW + pc0 + e];
#pragma unroll
        for (int e = 0; e < 20; e += 4)
            *(f32x4*)&r2[e] = *(const f32x4*)&V[(qcr + 2) * VROW + pc0 + e];
        float best = -1e30f; int bpc = 0;
#pragma unroll
        for (int kk = 0; kk < 16; ++kk) {
            float s = r0[kk] + r1[kk + 1] + r2[kk + 2];
            if (kk < kmax && s > best) { best = s; bpc = pc0 + kk; }
        }
        if (qc < OH) {
            unsigned u = __float_as_uint(best);
            u = (best >= 0.f) ? (u | 0x80000000u) : ~u;
            unsigned long long key = ((unsigned long long)u << 12)
                                   | (unsigned)((63 - (pr0 + k)) << 6)
                                   | (unsigned)(63 - bpc);
            atomicMax(&keys[(size_t)z * NPATCH + (qr0 + k) * OH + qc], key);
        }
#pragma unroll
        for (int e = 0; e < 16; ++e) { A[e] = B[e]; B[e] = C[e]; }
    }
}

// -------- K4 (k_loss): decode keys -> match; loss via norm expansion --------
__global__ void k_loss(const unsigned short* __restrict__ Dbase,
                       const unsigned long long* __restrict__ keys,
                       const float* __restrict__ ssPb, const float* __restrict__ invPb,
                       const float* __restrict__ ssTb, const float* __restrict__ invTb,
                       float* __restrict__ out) {
    const int z = blockIdx.y;
    const unsigned short* D = Dbase + (size_t)z * NPIX * NPIX;
    const float* ssP  = ssPb  + z * NPIX;
    const float* invP = invPb + z * NPIX;
    const float* ssT  = ssTb  + z * NPIX;
    const float* invT = invTb + z * NPIX;
    int q = blockIdx.x * 256 + threadIdx.x;
    float acc = 0.f;
    if (q < NPATCH) {
        int qr = q / OH, qc = q - qr * OH;
        int qpix = qr * WW + qc;
        unsigned long long key = keys[(size_t)z * NPATCH + q];
        int mpr = 63 - (int)((key >> 6) & 63);
        int mpc = 63 - (int)(key & 63);
        int mpix = mpr * WW + mpc;
#pragma unroll
        for (int i = 0; i < 3; ++i)
#pragma unroll
            for (int j = 0; j < 3; ++j) {
                int off = i * WW + j;
                int y = qpix + off, x = mpix + off;
                float Dv = bf16_to_f32(D[(size_t)y * NPIX + x]);
                float nP = ssP[y] * invP[y];       // = ||p_y||
                float nT = ssT[x] * invT[x];
                acc += ssP[y] + ssT[x] - 2.f * Dv * nP * nT;
            }
    }
#pragma unroll
    for (int s = 32; s > 0; s >>= 1) acc += __shfl_down(acc, s, 64);
    if ((threadIdx.x & 63) == 0)
        atomicAdd(out, acc * (1.f / 35426304.f));  // / (4*3844*2304)
}

// ---------------------------------- launch ----------------------------------
extern "C" void kernel_launch(void* const* d_in, const int* in_sizes, int n_in,
                              void* d_out, int out_size, void* d_ws, size_t ws_size,
                              hipStream_t stream) {
    const float* pred = (const float*)d_in[0];
    const float* tgt  = (const float*)d_in[1];
    char* ws = (char*)d_ws;
    // ws layout (bytes), ws_size = 256 MiB:
    // D(bf16, 4 batches) 128MB | Xn 8MB | Tn 8MB | norms 4x64KB | keys 123KB
    unsigned short*     Dws  = (unsigned short*)(ws);
    __hip_bfloat16*     Xn   = (__hip_bfloat16*)(ws + 134217728);
    __hip_bfloat16*     Tn   = (__hip_bfloat16*)(ws + 142606336);
    float*              ssP  = (float*)(ws + 150994944);
    float*              invP = (float*)(ws + 151060480);
    float*              ssT  = (float*)(ws + 151126016);
    float*              invT = (float*)(ws + 151191552);
    unsigned long long* keys = (unsigned long long*)(ws + 151257088);

    k_prep<<<dim3(64, 8), 256, 0, stream>>>(pred, tgt, Xn, Tn, ssP, invP, ssT, invT,
                                            keys, (float*)d_out);
    k_gemm<<<dim3(32, 32, 4), 512, 0, stream>>>(Xn, Tn, Dws);
    k_score<<<dim3(123, 8, 4), 256, 0, stream>>>(Dws, keys);
    k_loss<<<dim3(16, 4), 256, 0, stream>>>(Dws, keys, ssP, invP, ssT, invT,
                                            (float*)d_out);
}